// Round 2
// baseline (181.150 us; speedup 1.0000x reference)
//
#include <hip/hip_runtime.h>
#include <hip/hip_bf16.h>
#include <math.h>

typedef unsigned short u16;
typedef _Float16 f16x8 __attribute__((ext_vector_type(8)));
typedef float    f32x16 __attribute__((ext_vector_type(16)));
typedef u16      u16x8  __attribute__((ext_vector_type(8)));
typedef u16      u16x4  __attribute__((ext_vector_type(4)));

#define BATCH 16
#define T0 64000
#define T1 32000
#define T2 16000
#define T3 8000
#define NT3 250          // t3 outputs per mega block; 32 blocks x 250 = 8000 exactly
#define NBLKX 32
#define NROWS1 1040      // local y1 rows staged (520 LDS lines)

static __device__ __forceinline__ u16 f2h(float f) {
    _Float16 h = (_Float16)f;
    u16 u;
    __builtin_memcpy(&u, &h, 2);
    return u;
}

// ---------------- weight prep (f16, transposed for coalesced A-frag reads)
// + pooled/cnt zero
// a2t[kk][g][o][j]: kk 0..8, g=0..3 (i-granule), o=0..63, j=0..7 (i=8g+j)   18432 u16
// a3t[kk][g][o][j]: kk 0..8, g=0..7,              o=0..127, j=0..7          73728 u16
__global__ __launch_bounds__(256) void prep_w_k(const float* __restrict__ w2,
                                                const float* __restrict__ w3,
                                                u16* __restrict__ a2t,
                                                u16* __restrict__ a3t,
                                                float* __restrict__ pooled,
                                                int* __restrict__ cnt) {
    int idx = blockIdx.x * 256 + threadIdx.x;
    if (idx < 18432) {
        int j = idx & 7, o = (idx >> 3) & 63, g = (idx >> 9) & 3, kk = idx >> 11;
        a2t[idx] = f2h(w2[(o * 32 + g * 8 + j) * 9 + kk]);
    } else if (idx < 18432 + 73728) {
        int jdx = idx - 18432;
        int j = jdx & 7, o = (jdx >> 3) & 127, g = (jdx >> 10) & 7, kk = jdx >> 13;
        a3t[jdx] = f2h(w3[(o * 64 + g * 8 + j) * 9 + kk]);
    } else if (idx < 18432 + 73728 + 2048) {
        pooled[idx - 18432 - 73728] = 0.f;
    } else if (idx < 18432 + 73728 + 2048 + 16) {
        cnt[idx - 18432 - 73728 - 2048] = 0;
    }
}

// ---------------- mega: conv1(VALU) -> conv2(MFMA, in-place LDS) -> conv3(MFMA)+pool
// block = 512 thr (8 waves), t3 in [r0, r0+250), batch b. LDS: 520 lines x 128 B.
// Phase A: y1 rows l1 pair-packed 2/line, slot (pp*4+g)^(rr&7).
// Phase B (merged chunks): single kk loop keeps acc2 for BOTH 256-row chunks live;
//   A-frags loaded once (was twice); ALL y1 reads (lines <= 515 < 520) precede the
//   single barrier, then y2 overwrites lines [0,511]. Barriers 4 -> 2.
// Phase C: reads y2 lines 2*nl+kk (<= 518 < 520); columns nl >= 250 consume stale
//   (finite) data and are masked in the epilogue.
// Tail: last block per batch (atomic counter) computes feats (128x128 matmul +
//   amp normalization) -> featbuf; removes the separate feats_k dispatch.
// launch_bounds(512,4): 4 waves/EU min => VGPR <= 128 (merged Phase B holds
// acc2[2][2]=64 + af=16 + addressing live).
__global__ __launch_bounds__(512, 4) void mega_k(const float* __restrict__ audio,
                                                 const float* __restrict__ w1,
                                                 const float* __restrict__ b1,
                                                 const u16* __restrict__ a2t,
                                                 const float* __restrict__ b2,
                                                 const u16* __restrict__ a3t,
                                                 const float* __restrict__ b3,
                                                 float* __restrict__ pooled,
                                                 int* __restrict__ cnt,
                                                 const float* __restrict__ wl,
                                                 const float* __restrict__ bl,
                                                 float* __restrict__ featbuf) {
    __shared__ u16 sm[520 * 64];           // 66,560 B
    const int tid = threadIdx.x;
    const int b = blockIdx.y;
    const int r0 = blockIdx.x * NT3;
    const int lane = tid & 63, wv = tid >> 6;          // wv 0..7
    const int ls = lane >> 5, ln = lane & 31;

    // ---- Phase A: conv1 into LDS (y1 local rows 0..1039; global t1 = 4*r0-12+l1)
    {
        const float* ar = audio + (size_t)b * T0;
        #pragma unroll
        for (int rep = 0; rep < 3; ++rep) {
            int l1 = rep * 512 + tid;
            if (l1 >= NROWS1) break;
            int t1 = 4 * r0 - 12 + l1;
            int rr = l1 >> 1, pp = l1 & 1;
            if (t1 < 0 || t1 >= T1) {
                u16x8 z;
                #pragma unroll
                for (int q = 0; q < 8; ++q) z[q] = 0;
                #pragma unroll
                for (int g = 0; g < 4; ++g) {
                    int slot = (pp * 4 + g) ^ (rr & 7);
                    *(u16x8*)(sm + rr * 64 + slot * 8) = z;
                }
            } else {
                int base = 2 * t1 - 4;
                float x[9];
                #pragma unroll
                for (int k = 0; k < 9; ++k) {
                    int t0v = base + k;
                    x[k] = (t0v >= 0 && t0v < T0) ? ar[t0v] : 0.f;
                }
                #pragma unroll
                for (int g = 0; g < 4; ++g) {
                    u16x8 v;
                    #pragma unroll
                    for (int j = 0; j < 8; ++j) {
                        int ch = g * 8 + j;
                        float acc = b1[ch];
                        #pragma unroll
                        for (int k = 0; k < 9; ++k) acc = fmaf(x[k], w1[ch * 9 + k], acc);
                        v[j] = f2h(fmaxf(acc, 0.f));
                    }
                    int slot = (pp * 4 + g) ^ (rr & 7);
                    *(u16x8*)(sm + rr * 64 + slot * 8) = v;
                }
            }
        }
    }
    __syncthreads();

    // ---- Phase B: conv2, both 256-row chunks in one kk loop (A-frags loaded once)
    {
        f32x16 acc2[2][2];                  // [cc][mi]
        #pragma unroll
        for (int cc = 0; cc < 2; ++cc)
            #pragma unroll
            for (int mi = 0; mi < 2; ++mi)
                #pragma unroll
                for (int q = 0; q < 16; ++q) acc2[cc][mi][q] = 0.f;
        #pragma unroll 3
        for (int kk = 0; kk < 9; ++kk) {
            const u16* ap = a2t + kk * 2048;
            f16x8 af[2][2];
            #pragma unroll
            for (int step = 0; step < 2; ++step) {
                af[step][0] = *(const f16x8*)(ap + (2 * step + ls) * 512 + ln * 8);
                af[step][1] = *(const f16x8*)(ap + (2 * step + ls) * 512 + (32 + ln) * 8);
            }
            int pp = kk & 1, kh = kk >> 1;
            #pragma unroll
            for (int cc = 0; cc < 2; ++cc) {
                int nl = cc * 256 + 32 * wv + ln;
                int rr = nl + kh;
                #pragma unroll
                for (int step = 0; step < 2; ++step) {
                    int slot = (pp * 4 + 2 * step + ls) ^ (rr & 7);
                    f16x8 bfB = *(const f16x8*)(sm + rr * 64 + slot * 8);
                    acc2[cc][0] = __builtin_amdgcn_mfma_f32_32x32x16_f16(af[step][0], bfB, acc2[cc][0], 0, 0, 0);
                    acc2[cc][1] = __builtin_amdgcn_mfma_f32_32x32x16_f16(af[step][1], bfB, acc2[cc][1], 0, 0, 0);
                }
            }
        }
        __syncthreads();                    // all y1 reads done before overwrite
        #pragma unroll
        for (int cc = 0; cc < 2; ++cc) {
            int l2 = cc * 256 + 32 * wv + ln;
            int t2 = 2 * r0 - 4 + l2;
            bool valid = (t2 >= 0) && (t2 < T2);
            #pragma unroll
            for (int mi = 0; mi < 2; ++mi)
                #pragma unroll
                for (int q = 0; q < 4; ++q) {
                    u16x4 v;
                    #pragma unroll
                    for (int d = 0; d < 4; ++d) {
                        int o = 32 * mi + 8 * q + 4 * ls + d;
                        float xv = valid ? fmaxf(acc2[cc][mi][4 * q + d] + b2[o], 0.f) : 0.f;
                        v[d] = f2h(xv);
                    }
                    int gy = 4 * mi + q;
                    int sy = gy ^ ((l2 >> 1) & 7);
                    *(u16x4*)(sm + l2 * 64 + sy * 8 + ls * 4) = v;
                }
        }
        __syncthreads();
    }

    // ---- Phase C: conv3 MFMA + mean-pool (M=128 x N=256; 2x4 waves of 64x64)
    const int mh = wv & 1, nh = wv >> 1;               // mh 0..1, nh 0..3
    f32x16 acc3[2][2];
    #pragma unroll
    for (int mi = 0; mi < 2; ++mi)
        #pragma unroll
        for (int ni = 0; ni < 2; ++ni)
            #pragma unroll
            for (int q = 0; q < 16; ++q) acc3[mi][ni][q] = 0.f;

    f16x8 bf[2][4];
    #pragma unroll 3
    for (int kk = 0; kk < 9; ++kk) {
        const u16* ap = a3t + kk * 8192;
        {
            #pragma unroll
            for (int ni = 0; ni < 2; ++ni) {
                int nl = 64 * nh + 32 * ni + ln;
                int l2 = 2 * nl + kk;                  // <= 518 < 520
                int rrC = nl + (kk >> 1);
                #pragma unroll
                for (int step = 0; step < 4; ++step) {
                    int sy = (2 * step + ls) ^ (rrC & 7);
                    bf[ni][step] = *(const f16x8*)(sm + l2 * 64 + sy * 8);
                }
            }
        }
        #pragma unroll
        for (int step = 0; step < 4; ++step) {
            f16x8 af0 = *(const f16x8*)(ap + (2 * step + ls) * 1024 + (64 * mh + ln) * 8);
            f16x8 af1 = *(const f16x8*)(ap + (2 * step + ls) * 1024 + (64 * mh + 32 + ln) * 8);
            #pragma unroll
            for (int ni = 0; ni < 2; ++ni) {
                acc3[0][ni] = __builtin_amdgcn_mfma_f32_32x32x16_f16(af0, bf[ni][step], acc3[0][ni], 0, 0, 0);
                acc3[1][ni] = __builtin_amdgcn_mfma_f32_32x32x16_f16(af1, bf[ni][step], acc3[1][ni], 0, 0, 0);
            }
        }
    }

    // epilogue: bias+relu, mask nl>=250, per-wave partials -> LDS reduce -> atomics
    float loc[32];
    #pragma unroll
    for (int mi = 0; mi < 2; ++mi)
        #pragma unroll
        for (int r = 0; r < 16; ++r) {
            int o = 64 * mh + 32 * mi + (r & 3) + 8 * (r >> 2) + 4 * ls;
            float bias = b3[o];
            float s = 0.f;
            #pragma unroll
            for (int ni = 0; ni < 2; ++ni) {
                int nl = 64 * nh + 32 * ni + ln;
                float v = fmaxf(acc3[mi][ni][r] + bias, 0.f);
                s += (nl < NT3) ? v : 0.f;
            }
            loc[mi * 16 + r] = s;
        }
    __syncthreads();
    float* smf = (float*)sm;               // [4 nh][128 o][32 ln] = 64 KB <= 66,560 B
    #pragma unroll
    for (int mi = 0; mi < 2; ++mi)
        #pragma unroll
        for (int r = 0; r < 16; ++r) {
            int o = 64 * mh + 32 * mi + (r & 3) + 8 * (r >> 2) + 4 * ls;
            smf[nh * 4096 + o * 32 + ln] = loc[mi * 16 + r];
        }
    __syncthreads();
    if (tid < 128) {
        int o = tid;
        float s = 0.f;
        #pragma unroll
        for (int j = 0; j < 32; ++j) {
            int col = (j + o) & 31;
            s += smf[o * 32 + col] + smf[4096 + o * 32 + col]
               + smf[8192 + o * 32 + col] + smf[12288 + o * 32 + col];
        }
        atomicAdd(&pooled[b * 128 + o], s);
    }

    // ---- tail: last block of this batch computes feats (was feats_k)
    __threadfence();                        // order pooled atomics before cnt inc
    __syncthreads();                        // all lanes' atomics issued+fenced
    int* smi = (int*)sm;
    if (tid == 0) {
        int done = atomicAdd(&cnt[b], 1);
        smi[0] = (done == NBLKX - 1) ? 1 : 0;
    }
    __syncthreads();
    if (smi[0]) {
        float* pl = (float*)sm + 64;        // past the flag word
        if (tid < 128)
            pl[tid] = atomicAdd(&pooled[b * 128 + tid], 0.f) * (1.0f / 8000.0f);
        __syncthreads();
        if (tid < 128) {
            float feat = bl[tid];
            #pragma unroll 8
            for (int i = 0; i < 128; ++i) feat = fmaf(pl[i], wl[tid * 128 + i], feat);
            if (tid < 64) {                 // wave 0: amps + normalize
                float r = fmaxf(feat, 0.f);
                float s = r;
                #pragma unroll
                for (int off = 32; off > 0; off >>= 1) s += __shfl_xor(s, off);
                featbuf[b * 128 + tid] = r / (s + 1e-6f);
            } else {                        // noise_mag raw
                featbuf[b * 128 + tid] = feat;
            }
        }
    }
}

// ---------------- synthesis: Chebyshev sin-recurrence, 4 samples/thread, float4 I/O
// sin(2*pi*(h+1)*u) = 2*cos(2*pi*u)*sin(2*pi*h*u) - sin(2*pi*(h-1)*u)
__global__ __launch_bounds__(256) void synth_k(const float* __restrict__ f0,
                                               const float* __restrict__ wn,
                                               const float* __restrict__ featbuf,
                                               float* __restrict__ out) {
    const int tid = threadIdx.x;
    const int b = blockIdx.y;
    __shared__ float sa[64];
    __shared__ float nm[64];
    if (tid < 64) sa[tid] = featbuf[b * 128 + tid];
    else if (tid < 128) nm[tid - 64] = featbuf[b * 128 + tid];
    __syncthreads();

    const int t0v = blockIdx.x * 1024 + tid * 4;
    if (t0v >= T0) return;                  // last block tail (after the barrier)

    const float4 fv = *(const float4*)(f0 + (size_t)b * T0 + t0v);
    const float4 wv = *(const float4*)(wn + (size_t)b * T0 + t0v);

    float sc[4], sp[4], tc[4], ac[4];
    #pragma unroll
    for (int s = 0; s < 4; ++s) {
        // u = f0 * t * 4/63999 (linspace incl endpoint); frac in double (phase can
        // reach ~1e5 revolutions), then recurrence runs entirely in fp32.
        double u = (double)((&fv.x)[s]) * ((double)(t0v + s) * (4.0 / 63999.0));
        float uf = (float)(u - floor(u));
        sc[s] = __builtin_amdgcn_sinf(uf);           // sin(2*pi*u)
        tc[s] = 2.0f * __builtin_amdgcn_cosf(uf);    // 2*cos(2*pi*u)
        sp[s] = 0.f;
        ac[s] = 0.f;
    }
    #pragma unroll
    for (int h = 0; h < 64; ++h) {
        float a = sa[h];
        #pragma unroll
        for (int s = 0; s < 4; ++s) {
            ac[s] = fmaf(a, sc[s], ac[s]);
            float sn = fmaf(tc[s], sc[s], -sp[s]);   // sin(2*pi*(h+2)*u)
            sp[s] = sc[s];
            sc[s] = sn;
        }
    }
    float4 o;
    #pragma unroll
    for (int s = 0; s < 4; ++s)
        (&o.x)[s] = ac[s] + (&wv.x)[s] * nm[(t0v + s) / 1000];
    *(float4*)(out + (size_t)b * T0 + t0v) = o;
}

extern "C" void kernel_launch(void* const* d_in, const int* in_sizes, int n_in,
                              void* d_out, int out_size, void* d_ws, size_t ws_size,
                              hipStream_t stream) {
    const float* audio = (const float*)d_in[0];
    const float* f0    = (const float*)d_in[1];
    const float* wn    = (const float*)d_in[2];
    const float* w1    = (const float*)d_in[3];
    const float* b1    = (const float*)d_in[4];
    const float* w2    = (const float*)d_in[5];
    const float* b2    = (const float*)d_in[6];
    const float* w3    = (const float*)d_in[7];
    const float* b3    = (const float*)d_in[8];
    const float* wl    = (const float*)d_in[9];
    const float* bl    = (const float*)d_in[10];
    float* out = (float*)d_out;

    char* ws = (char*)d_ws;
    float* pooled  = (float*)(ws);                 // 2048 f32 (zeroed by prep_w_k)
    int*   cnt     = (int*)(ws + 8192);            // 16 int (zeroed by prep_w_k)
    float* featbuf = (float*)(ws + 8448);          // 2048 f32 (written by mega tail)
    u16*   a2t     = (u16*)(ws + 16640);           // 18432 u16
    u16*   a3t     = (u16*)(ws + 16640 + 36864);   // 73728 u16

    prep_w_k<<<369, 256, 0, stream>>>(w2, w3, a2t, a3t, pooled, cnt);
    mega_k<<<dim3(NBLKX, BATCH), 512, 0, stream>>>(audio, w1, b1, a2t, b2, a3t, b3,
                                                   pooled, cnt, wl, bl, featbuf);
    synth_k<<<dim3((T0 + 1023) / 1024, BATCH), 256, 0, stream>>>(f0, wn, featbuf, out);
}

// Round 3
// 181.127 us; speedup vs baseline: 1.0001x; 1.0001x over previous
//
#include <hip/hip_runtime.h>
#include <hip/hip_bf16.h>
#include <math.h>

typedef unsigned short u16;
typedef _Float16 f16x8 __attribute__((ext_vector_type(8)));
typedef float    f32x16 __attribute__((ext_vector_type(16)));
typedef u16      u16x8  __attribute__((ext_vector_type(8)));
typedef u16      u16x4  __attribute__((ext_vector_type(4)));

#define BATCH 16
#define T0 64000
#define T1 32000
#define T2 16000
#define T3 8000
#define NT3 250          // t3 outputs per mega block; 32 blocks x 250 = 8000 exactly
#define NBLKX 32
#define NROWS1 1040      // local y1 rows staged (520 LDS lines)

static __device__ __forceinline__ u16 f2h(float f) {
    _Float16 h = (_Float16)f;
    u16 u;
    __builtin_memcpy(&u, &h, 2);
    return u;
}

// ---------------- weight prep (f16, transposed for coalesced A-frag reads)
// + pooled/cnt zero
// a2t[kk][g][o][j]: kk 0..8, g=0..3 (i-granule), o=0..63, j=0..7 (i=8g+j)   18432 u16
// a3t[kk][g][o][j]: kk 0..8, g=0..7,              o=0..127, j=0..7          73728 u16
// a1t[g][o][j]:     g=0..1, o=0..31, j=0..7; A[o][i=8g+j] = w1 tap i (i<9),
//                   b1[o] (i==9, bias row; X row 9 is const 1.0), 0 else.    512 u16
__global__ __launch_bounds__(256) void prep_w_k(const float* __restrict__ w1,
                                                const float* __restrict__ b1,
                                                const float* __restrict__ w2,
                                                const float* __restrict__ w3,
                                                u16* __restrict__ a1t,
                                                u16* __restrict__ a2t,
                                                u16* __restrict__ a3t,
                                                float* __restrict__ pooled,
                                                int* __restrict__ cnt) {
    int idx = blockIdx.x * 256 + threadIdx.x;
    if (idx < 18432) {
        int j = idx & 7, o = (idx >> 3) & 63, g = (idx >> 9) & 3, kk = idx >> 11;
        a2t[idx] = f2h(w2[(o * 32 + g * 8 + j) * 9 + kk]);
    } else if (idx < 18432 + 73728) {
        int jdx = idx - 18432;
        int j = jdx & 7, o = (jdx >> 3) & 127, g = (jdx >> 10) & 7, kk = jdx >> 13;
        a3t[jdx] = f2h(w3[(o * 64 + g * 8 + j) * 9 + kk]);
    } else if (idx < 18432 + 73728 + 2048) {
        pooled[idx - 18432 - 73728] = 0.f;
    } else if (idx < 18432 + 73728 + 2048 + 16) {
        cnt[idx - 18432 - 73728 - 2048] = 0;
    } else if (idx < 18432 + 73728 + 2048 + 16 + 512) {
        int jdx = idx - (18432 + 73728 + 2048 + 16);
        int j = jdx & 7, o = (jdx >> 3) & 31, g = jdx >> 8;
        int i = 8 * g + j;
        float v = (i < 9) ? w1[o * 9 + i] : ((i == 9) ? b1[o] : 0.f);
        a1t[jdx] = f2h(v);
    }
}

// ---------------- mega: conv1(MFMA for interior blocks) -> conv2(MFMA, in-place LDS)
//                  -> conv3(MFMA)+pool -> feats tail (last block per batch)
// block = 512 thr (8 waves), t3 in [r0, r0+250), batch b. LDS: 520 lines x 128 B.
// Phase A fast (blocks 1..30, fully in-bounds): conv1 as 2 MFMAs per 32-column tile
//   (x split hi/lo f16 to keep ~f32 input precision; bias folded as K-row 9 = 1.0).
//   C layout: ch = (r&3)+8*(r>>2)+4*ls, col = ln -> u16x4 quads to the same
//   pair-packed slot layout Phase B reads: line rr=l1>>1, slot (pp*4+g)^(rr&7).
// Phase A slow (blocks 0, 31): scalar path with exact zero-padding.
// Phase B: 2 chunks of 256 y2 rows, in-place write-back (reads lines <= 515 before
//   barrier; writes [256cc, 256cc+255] after). acc held per-chunk only: fits 128-reg
//   budget at launch_bounds(512,2) -- R2's merged-chunk variant spilled (VGPR cap).
// Phase C: reads y2 lines 2*nl+kk (<= 518 < 520); columns nl >= 250 masked in epilogue.
__global__ __launch_bounds__(512, 2) void mega_k(const float* __restrict__ audio,
                                                 const float* __restrict__ w1,
                                                 const float* __restrict__ b1,
                                                 const u16* __restrict__ a1t,
                                                 const u16* __restrict__ a2t,
                                                 const float* __restrict__ b2,
                                                 const u16* __restrict__ a3t,
                                                 const float* __restrict__ b3,
                                                 float* __restrict__ pooled,
                                                 int* __restrict__ cnt,
                                                 const float* __restrict__ wl,
                                                 const float* __restrict__ bl,
                                                 float* __restrict__ featbuf) {
    __shared__ u16 sm[520 * 64];           // 66,560 B
    const int tid = threadIdx.x;
    const int b = blockIdx.y;
    const int r0 = blockIdx.x * NT3;
    const int lane = tid & 63, wv = tid >> 6;          // wv 0..7
    const int ls = lane >> 5, ln = lane & 31;

    // ---- Phase A: conv1 into LDS (y1 local rows 0..1039; global t1 = 4*r0-12+l1)
    const float* ar = audio + (size_t)b * T0;
    if (blockIdx.x != 0 && blockIdx.x != NBLKX - 1) {
        // fast path: every t1g in [4r0-12, 4r0+1043] and every audio index in-bounds
        f16x8 a1f = *(const f16x8*)(a1t + ls * 256 + ln * 8);
        for (int tile = wv; tile < 33; tile += 8) {
            int l1 = tile * 32 + ln;
            int t1g = 4 * r0 - 12 + l1;
            f16x8 xh, xl;
            if (ls == 0) {
                const float* p = ar + 2 * t1g - 4;     // 8B-aligned
                #pragma unroll
                for (int q = 0; q < 4; ++q) {
                    float2 x2 = *(const float2*)(p + 2 * q);
                    _Float16 h0 = (_Float16)x2.x;
                    _Float16 h1 = (_Float16)x2.y;
                    xh[2 * q]     = h0;
                    xh[2 * q + 1] = h1;
                    xl[2 * q]     = (_Float16)(x2.x - (float)h0);
                    xl[2 * q + 1] = (_Float16)(x2.y - (float)h1);
                }
            } else {
                float x8 = ar[2 * t1g + 4];            // tap k=8
                _Float16 h = (_Float16)x8;
                #pragma unroll
                for (int q = 0; q < 8; ++q) { xh[q] = (_Float16)0.f; xl[q] = (_Float16)0.f; }
                xh[0] = h;
                xh[1] = (_Float16)1.0f;                // bias row
                xl[0] = (_Float16)(x8 - (float)h);
            }
            f32x16 acc;
            #pragma unroll
            for (int q = 0; q < 16; ++q) acc[q] = 0.f;
            acc = __builtin_amdgcn_mfma_f32_32x32x16_f16(a1f, xl, acc, 0, 0, 0);
            acc = __builtin_amdgcn_mfma_f32_32x32x16_f16(a1f, xh, acc, 0, 0, 0);
            if (l1 < NROWS1) {
                int rr = l1 >> 1, pp = l1 & 1;
                #pragma unroll
                for (int gq = 0; gq < 4; ++gq) {
                    u16x4 v;
                    #pragma unroll
                    for (int d = 0; d < 4; ++d)
                        v[d] = f2h(fmaxf(acc[4 * gq + d], 0.f));
                    int slot = (pp * 4 + gq) ^ (rr & 7);
                    *(u16x4*)(sm + rr * 64 + slot * 8 + ls * 4) = v;
                }
            }
        }
    } else {
        // slow path (edge blocks): scalar conv1 with exact zero-padding
        #pragma unroll
        for (int rep = 0; rep < 3; ++rep) {
            int l1 = rep * 512 + tid;
            if (l1 >= NROWS1) break;
            int t1 = 4 * r0 - 12 + l1;
            int rr = l1 >> 1, pp = l1 & 1;
            if (t1 < 0 || t1 >= T1) {
                u16x8 z;
                #pragma unroll
                for (int q = 0; q < 8; ++q) z[q] = 0;
                #pragma unroll
                for (int g = 0; g < 4; ++g) {
                    int slot = (pp * 4 + g) ^ (rr & 7);
                    *(u16x8*)(sm + rr * 64 + slot * 8) = z;
                }
            } else {
                int base = 2 * t1 - 4;
                float x[9];
                #pragma unroll
                for (int k = 0; k < 9; ++k) {
                    int t0v = base + k;
                    x[k] = (t0v >= 0 && t0v < T0) ? ar[t0v] : 0.f;
                }
                #pragma unroll
                for (int g = 0; g < 4; ++g) {
                    u16x8 v;
                    #pragma unroll
                    for (int j = 0; j < 8; ++j) {
                        int ch = g * 8 + j;
                        float acc = b1[ch];
                        #pragma unroll
                        for (int k = 0; k < 9; ++k) acc = fmaf(x[k], w1[ch * 9 + k], acc);
                        v[j] = f2h(fmaxf(acc, 0.f));
                    }
                    int slot = (pp * 4 + g) ^ (rr & 7);
                    *(u16x8*)(sm + rr * 64 + slot * 8) = v;
                }
            }
        }
    }
    __syncthreads();

    // ---- Phase B: conv2 in 2 chunks of 256 y2 rows, in-place write-back
    for (int cc = 0; cc < 2; ++cc) {
        int nl = cc * 256 + 32 * wv + ln;   // this lane's y2 row (B column)
        f32x16 acc2[2];
        #pragma unroll
        for (int mi = 0; mi < 2; ++mi)
            #pragma unroll
            for (int q = 0; q < 16; ++q) acc2[mi][q] = 0.f;
        f16x8 bfB[2];
        #pragma unroll 3
        for (int kk = 0; kk < 9; ++kk) {
            {
                int rr = nl + (kk >> 1);
                int pp = kk & 1;
                #pragma unroll
                for (int step = 0; step < 2; ++step) {
                    int slot = (pp * 4 + 2 * step + ls) ^ (rr & 7);
                    bfB[step] = *(const f16x8*)(sm + rr * 64 + slot * 8);
                }
            }
            const u16* ap = a2t + kk * 2048;
            #pragma unroll
            for (int step = 0; step < 2; ++step) {
                f16x8 af0 = *(const f16x8*)(ap + (2 * step + ls) * 512 + ln * 8);
                f16x8 af1 = *(const f16x8*)(ap + (2 * step + ls) * 512 + (32 + ln) * 8);
                acc2[0] = __builtin_amdgcn_mfma_f32_32x32x16_f16(af0, bfB[step], acc2[0], 0, 0, 0);
                acc2[1] = __builtin_amdgcn_mfma_f32_32x32x16_f16(af1, bfB[step], acc2[1], 0, 0, 0);
            }
        }
        __syncthreads();                    // all chunk reads done before overwrite
        int l2 = nl;
        int t2 = 2 * r0 - 4 + l2;
        bool valid = (t2 >= 0) && (t2 < T2);
        #pragma unroll
        for (int mi = 0; mi < 2; ++mi)
            #pragma unroll
            for (int q = 0; q < 4; ++q) {
                u16x4 v;
                #pragma unroll
                for (int d = 0; d < 4; ++d) {
                    int o = 32 * mi + 8 * q + 4 * ls + d;
                    float xv = valid ? fmaxf(acc2[mi][4 * q + d] + b2[o], 0.f) : 0.f;
                    v[d] = f2h(xv);
                }
                int gy = 4 * mi + q;
                int sy = gy ^ ((l2 >> 1) & 7);
                *(u16x4*)(sm + l2 * 64 + sy * 8 + ls * 4) = v;
            }
        __syncthreads();
    }

    // ---- Phase C: conv3 MFMA + mean-pool (M=128 x N=256; 2x4 waves of 64x64)
    const int mh = wv & 1, nh = wv >> 1;               // mh 0..1, nh 0..3
    f32x16 acc3[2][2];
    #pragma unroll
    for (int mi = 0; mi < 2; ++mi)
        #pragma unroll
        for (int ni = 0; ni < 2; ++ni)
            #pragma unroll
            for (int q = 0; q < 16; ++q) acc3[mi][ni][q] = 0.f;

    f16x8 bf[2][4];
    #pragma unroll 3
    for (int kk = 0; kk < 9; ++kk) {
        const u16* ap = a3t + kk * 8192;
        {
            #pragma unroll
            for (int ni = 0; ni < 2; ++ni) {
                int nl = 64 * nh + 32 * ni + ln;
                int l2 = 2 * nl + kk;                  // <= 518 < 520
                int rrC = nl + (kk >> 1);
                #pragma unroll
                for (int step = 0; step < 4; ++step) {
                    int sy = (2 * step + ls) ^ (rrC & 7);
                    bf[ni][step] = *(const f16x8*)(sm + l2 * 64 + sy * 8);
                }
            }
        }
        #pragma unroll
        for (int step = 0; step < 4; ++step) {
            f16x8 af0 = *(const f16x8*)(ap + (2 * step + ls) * 1024 + (64 * mh + ln) * 8);
            f16x8 af1 = *(const f16x8*)(ap + (2 * step + ls) * 1024 + (64 * mh + 32 + ln) * 8);
            #pragma unroll
            for (int ni = 0; ni < 2; ++ni) {
                acc3[0][ni] = __builtin_amdgcn_mfma_f32_32x32x16_f16(af0, bf[ni][step], acc3[0][ni], 0, 0, 0);
                acc3[1][ni] = __builtin_amdgcn_mfma_f32_32x32x16_f16(af1, bf[ni][step], acc3[1][ni], 0, 0, 0);
            }
        }
    }

    // epilogue: bias+relu, mask nl>=250, per-wave partials -> LDS reduce -> atomics
    float loc[32];
    #pragma unroll
    for (int mi = 0; mi < 2; ++mi)
        #pragma unroll
        for (int r = 0; r < 16; ++r) {
            int o = 64 * mh + 32 * mi + (r & 3) + 8 * (r >> 2) + 4 * ls;
            float bias = b3[o];
            float s = 0.f;
            #pragma unroll
            for (int ni = 0; ni < 2; ++ni) {
                int nl = 64 * nh + 32 * ni + ln;
                float v = fmaxf(acc3[mi][ni][r] + bias, 0.f);
                s += (nl < NT3) ? v : 0.f;
            }
            loc[mi * 16 + r] = s;
        }
    __syncthreads();
    float* smf = (float*)sm;               // [4 nh][128 o][32 ln] = 64 KB <= 66,560 B
    #pragma unroll
    for (int mi = 0; mi < 2; ++mi)
        #pragma unroll
        for (int r = 0; r < 16; ++r) {
            int o = 64 * mh + 32 * mi + (r & 3) + 8 * (r >> 2) + 4 * ls;
            smf[nh * 4096 + o * 32 + ln] = loc[mi * 16 + r];
        }
    __syncthreads();
    if (tid < 128) {
        int o = tid;
        float s = 0.f;
        #pragma unroll
        for (int j = 0; j < 32; ++j) {
            int col = (j + o) & 31;
            s += smf[o * 32 + col] + smf[4096 + o * 32 + col]
               + smf[8192 + o * 32 + col] + smf[12288 + o * 32 + col];
        }
        atomicAdd(&pooled[b * 128 + o], s);
    }

    // ---- tail: last block of this batch computes feats (was feats_k)
    __threadfence();                        // order pooled atomics before cnt inc
    __syncthreads();                        // all lanes' atomics issued+fenced
    int* smi = (int*)sm;
    if (tid == 0) {
        int done = atomicAdd(&cnt[b], 1);
        smi[0] = (done == NBLKX - 1) ? 1 : 0;
    }
    __syncthreads();
    if (smi[0]) {
        float* pl = (float*)sm + 64;        // past the flag word
        if (tid < 128)
            pl[tid] = atomicAdd(&pooled[b * 128 + tid], 0.f) * (1.0f / 8000.0f);
        __syncthreads();
        if (tid < 128) {
            float feat = bl[tid];
            #pragma unroll 8
            for (int i = 0; i < 128; ++i) feat = fmaf(pl[i], wl[tid * 128 + i], feat);
            if (tid < 64) {                 // wave 0: amps + normalize
                float r = fmaxf(feat, 0.f);
                float s = r;
                #pragma unroll
                for (int off = 32; off > 0; off >>= 1) s += __shfl_xor(s, off);
                featbuf[b * 128 + tid] = r / (s + 1e-6f);
            } else {                        // noise_mag raw
                featbuf[b * 128 + tid] = feat;
            }
        }
    }
}

// ---------------- synthesis: Chebyshev sin-recurrence, 4 samples/thread, float4 I/O
// sin(2*pi*(h+1)*u) = 2*cos(2*pi*u)*sin(2*pi*h*u) - sin(2*pi*(h-1)*u)
__global__ __launch_bounds__(256) void synth_k(const float* __restrict__ f0,
                                               const float* __restrict__ wn,
                                               const float* __restrict__ featbuf,
                                               float* __restrict__ out) {
    const int tid = threadIdx.x;
    const int b = blockIdx.y;
    __shared__ float sa[64];
    __shared__ float nm[64];
    if (tid < 64) sa[tid] = featbuf[b * 128 + tid];
    else if (tid < 128) nm[tid - 64] = featbuf[b * 128 + tid];
    __syncthreads();

    const int t0v = blockIdx.x * 1024 + tid * 4;
    if (t0v >= T0) return;                  // last block tail (after the barrier)

    const float4 fv = *(const float4*)(f0 + (size_t)b * T0 + t0v);
    const float4 wv = *(const float4*)(wn + (size_t)b * T0 + t0v);

    float sc[4], sp[4], tc[4], ac[4];
    #pragma unroll
    for (int s = 0; s < 4; ++s) {
        // u = f0 * t * 4/63999 (linspace incl endpoint); frac in double (phase can
        // reach ~1e5 revolutions), then recurrence runs entirely in fp32.
        double u = (double)((&fv.x)[s]) * ((double)(t0v + s) * (4.0 / 63999.0));
        float uf = (float)(u - floor(u));
        sc[s] = __builtin_amdgcn_sinf(uf);           // sin(2*pi*u)
        tc[s] = 2.0f * __builtin_amdgcn_cosf(uf);    // 2*cos(2*pi*u)
        sp[s] = 0.f;
        ac[s] = 0.f;
    }
    #pragma unroll
    for (int h = 0; h < 64; ++h) {
        float a = sa[h];
        #pragma unroll
        for (int s = 0; s < 4; ++s) {
            ac[s] = fmaf(a, sc[s], ac[s]);
            float sn = fmaf(tc[s], sc[s], -sp[s]);   // sin(2*pi*(h+2)*u)
            sp[s] = sc[s];
            sc[s] = sn;
        }
    }
    float4 o;
    #pragma unroll
    for (int s = 0; s < 4; ++s)
        (&o.x)[s] = ac[s] + (&wv.x)[s] * nm[(t0v + s) / 1000];
    *(float4*)(out + (size_t)b * T0 + t0v) = o;
}

extern "C" void kernel_launch(void* const* d_in, const int* in_sizes, int n_in,
                              void* d_out, int out_size, void* d_ws, size_t ws_size,
                              hipStream_t stream) {
    const float* audio = (const float*)d_in[0];
    const float* f0    = (const float*)d_in[1];
    const float* wn    = (const float*)d_in[2];
    const float* w1    = (const float*)d_in[3];
    const float* b1    = (const float*)d_in[4];
    const float* w2    = (const float*)d_in[5];
    const float* b2    = (const float*)d_in[6];
    const float* w3    = (const float*)d_in[7];
    const float* b3    = (const float*)d_in[8];
    const float* wl    = (const float*)d_in[9];
    const float* bl    = (const float*)d_in[10];
    float* out = (float*)d_out;

    char* ws = (char*)d_ws;
    float* pooled  = (float*)(ws);                 // 2048 f32 (zeroed by prep_w_k)
    int*   cnt     = (int*)(ws + 8192);            // 16 int (zeroed by prep_w_k)
    float* featbuf = (float*)(ws + 8448);          // 2048 f32 (written by mega tail)
    u16*   a2t     = (u16*)(ws + 16640);           // 18432 u16
    u16*   a3t     = (u16*)(ws + 16640 + 36864);   // 73728 u16
    u16*   a1t     = (u16*)(ws + 16640 + 36864 + 147456);  // 512 u16

    prep_w_k<<<371, 256, 0, stream>>>(w1, b1, w2, w3, a1t, a2t, a3t, pooled, cnt);
    mega_k<<<dim3(NBLKX, BATCH), 512, 0, stream>>>(audio, w1, b1, a1t, a2t, b2, a3t, b3,
                                                   pooled, cnt, wl, bl, featbuf);
    synth_k<<<dim3((T0 + 1023) / 1024, BATCH), 256, 0, stream>>>(f0, wn, featbuf, out);
}

// Round 4
// 126.637 us; speedup vs baseline: 1.4305x; 1.4303x over previous
//
#include <hip/hip_runtime.h>
#include <hip/hip_bf16.h>
#include <math.h>

typedef unsigned short u16;
typedef _Float16 f16x8 __attribute__((ext_vector_type(8)));
typedef float    f32x16 __attribute__((ext_vector_type(16)));
typedef u16      u16x8  __attribute__((ext_vector_type(8)));
typedef u16      u16x4  __attribute__((ext_vector_type(4)));

#define BATCH 16
#define T0 64000
#define T1 32000
#define T2 16000
#define T3 8000
#define NT3 250          // t3 outputs per mega block; 32 blocks x 250 = 8000 exactly
#define NBLKX 32
#define NROWS1 1040      // local y1 rows staged (520 LDS lines)

static __device__ __forceinline__ u16 f2h(float f) {
    _Float16 h = (_Float16)f;
    u16 u;
    __builtin_memcpy(&u, &h, 2);
    return u;
}

// ---------------- weight prep (f16, transposed for coalesced A-frag reads)
// + pooled/cnt zero
// a2t[kk][g][o][j]: kk 0..8, g=0..3 (i-granule), o=0..63, j=0..7 (i=8g+j)   18432 u16
// a3t[kk][g][o][j]: kk 0..8, g=0..7,              o=0..127, j=0..7          73728 u16
// a1t[g][o][j]:     g=0..1, o=0..31, j=0..7; A[o][i=8g+j] = w1 tap i (i<9),
//                   b1[o] (i==9, bias row; X row 9 is const 1.0), 0 else.    512 u16
__global__ __launch_bounds__(256) void prep_w_k(const float* __restrict__ w1,
                                                const float* __restrict__ b1,
                                                const float* __restrict__ w2,
                                                const float* __restrict__ w3,
                                                u16* __restrict__ a1t,
                                                u16* __restrict__ a2t,
                                                u16* __restrict__ a3t,
                                                float* __restrict__ pooled,
                                                int* __restrict__ cnt) {
    int idx = blockIdx.x * 256 + threadIdx.x;
    if (idx < 18432) {
        int j = idx & 7, o = (idx >> 3) & 63, g = (idx >> 9) & 3, kk = idx >> 11;
        a2t[idx] = f2h(w2[(o * 32 + g * 8 + j) * 9 + kk]);
    } else if (idx < 18432 + 73728) {
        int jdx = idx - 18432;
        int j = jdx & 7, o = (jdx >> 3) & 127, g = (jdx >> 10) & 7, kk = jdx >> 13;
        a3t[jdx] = f2h(w3[(o * 64 + g * 8 + j) * 9 + kk]);
    } else if (idx < 18432 + 73728 + 2048) {
        pooled[idx - 18432 - 73728] = 0.f;
    } else if (idx < 18432 + 73728 + 2048 + 16) {
        cnt[idx - 18432 - 73728 - 2048] = 0;
    } else if (idx < 18432 + 73728 + 2048 + 16 + 512) {
        int jdx = idx - (18432 + 73728 + 2048 + 16);
        int j = jdx & 7, o = (jdx >> 3) & 31, g = jdx >> 8;
        int i = 8 * g + j;
        float v = (i < 9) ? w1[o * 9 + i] : ((i == 9) ? b1[o] : 0.f);
        a1t[jdx] = f2h(v);
    }
}

// ---------------- mega: conv1(MFMA for interior blocks) -> conv2(MFMA, in-place LDS)
//                  -> conv3(MFMA)+pool -> feats tail (last block per batch)
// block = 512 thr (8 waves), t3 in [r0, r0+250), batch b. LDS: 520 lines x 128 B.
// Phase A fast (blocks 1..30, fully in-bounds): conv1 as 2 MFMAs per 32-column tile
//   (x split hi/lo f16 to keep ~f32 input precision; bias folded as K-row 9 = 1.0).
// Phase A slow (blocks 0, 31): scalar path with exact zero-padding.
// Phase B: 2 chunks of 256 y2 rows, in-place write-back.
// Phase C: reads y2 lines 2*nl+kk (<= 518 < 520); columns nl >= 250 masked in epilogue.
// Tail: NO __threadfence() -- R2/R3 showed the device-scope fence (buffer_wbl2 L2
//   writeback, issued by all 512 blocks) cost ~55 us. It is also unnecessary: pooled
//   updates are device-scope atomics (coherent point, not the non-coherent L2 path),
//   and __syncthreads() drains vmcnt(0) before s_barrier, so the cnt atomicAdd is
//   release-ordered after the pooled atomics without any L2 writeback.
__global__ __launch_bounds__(512, 2) void mega_k(const float* __restrict__ audio,
                                                 const float* __restrict__ w1,
                                                 const float* __restrict__ b1,
                                                 const u16* __restrict__ a1t,
                                                 const u16* __restrict__ a2t,
                                                 const float* __restrict__ b2,
                                                 const u16* __restrict__ a3t,
                                                 const float* __restrict__ b3,
                                                 float* __restrict__ pooled,
                                                 int* __restrict__ cnt,
                                                 const float* __restrict__ wl,
                                                 const float* __restrict__ bl,
                                                 float* __restrict__ featbuf) {
    __shared__ u16 sm[520 * 64];           // 66,560 B
    const int tid = threadIdx.x;
    const int b = blockIdx.y;
    const int r0 = blockIdx.x * NT3;
    const int lane = tid & 63, wv = tid >> 6;          // wv 0..7
    const int ls = lane >> 5, ln = lane & 31;

    // ---- Phase A: conv1 into LDS (y1 local rows 0..1039; global t1 = 4*r0-12+l1)
    const float* ar = audio + (size_t)b * T0;
    if (blockIdx.x != 0 && blockIdx.x != NBLKX - 1) {
        // fast path: every t1g in [4r0-12, 4r0+1043] and every audio index in-bounds
        f16x8 a1f = *(const f16x8*)(a1t + ls * 256 + ln * 8);
        for (int tile = wv; tile < 33; tile += 8) {
            int l1 = tile * 32 + ln;
            int t1g = 4 * r0 - 12 + l1;
            f16x8 xh, xl;
            if (ls == 0) {
                const float* p = ar + 2 * t1g - 4;     // 8B-aligned
                #pragma unroll
                for (int q = 0; q < 4; ++q) {
                    float2 x2 = *(const float2*)(p + 2 * q);
                    _Float16 h0 = (_Float16)x2.x;
                    _Float16 h1 = (_Float16)x2.y;
                    xh[2 * q]     = h0;
                    xh[2 * q + 1] = h1;
                    xl[2 * q]     = (_Float16)(x2.x - (float)h0);
                    xl[2 * q + 1] = (_Float16)(x2.y - (float)h1);
                }
            } else {
                float x8 = ar[2 * t1g + 4];            // tap k=8
                _Float16 h = (_Float16)x8;
                #pragma unroll
                for (int q = 0; q < 8; ++q) { xh[q] = (_Float16)0.f; xl[q] = (_Float16)0.f; }
                xh[0] = h;
                xh[1] = (_Float16)1.0f;                // bias row
                xl[0] = (_Float16)(x8 - (float)h);
            }
            f32x16 acc;
            #pragma unroll
            for (int q = 0; q < 16; ++q) acc[q] = 0.f;
            acc = __builtin_amdgcn_mfma_f32_32x32x16_f16(a1f, xl, acc, 0, 0, 0);
            acc = __builtin_amdgcn_mfma_f32_32x32x16_f16(a1f, xh, acc, 0, 0, 0);
            if (l1 < NROWS1) {
                int rr = l1 >> 1, pp = l1 & 1;
                #pragma unroll
                for (int gq = 0; gq < 4; ++gq) {
                    u16x4 v;
                    #pragma unroll
                    for (int d = 0; d < 4; ++d)
                        v[d] = f2h(fmaxf(acc[4 * gq + d], 0.f));
                    int slot = (pp * 4 + gq) ^ (rr & 7);
                    *(u16x4*)(sm + rr * 64 + slot * 8 + ls * 4) = v;
                }
            }
        }
    } else {
        // slow path (edge blocks): scalar conv1 with exact zero-padding
        #pragma unroll
        for (int rep = 0; rep < 3; ++rep) {
            int l1 = rep * 512 + tid;
            if (l1 >= NROWS1) break;
            int t1 = 4 * r0 - 12 + l1;
            int rr = l1 >> 1, pp = l1 & 1;
            if (t1 < 0 || t1 >= T1) {
                u16x8 z;
                #pragma unroll
                for (int q = 0; q < 8; ++q) z[q] = 0;
                #pragma unroll
                for (int g = 0; g < 4; ++g) {
                    int slot = (pp * 4 + g) ^ (rr & 7);
                    *(u16x8*)(sm + rr * 64 + slot * 8) = z;
                }
            } else {
                int base = 2 * t1 - 4;
                float x[9];
                #pragma unroll
                for (int k = 0; k < 9; ++k) {
                    int t0v = base + k;
                    x[k] = (t0v >= 0 && t0v < T0) ? ar[t0v] : 0.f;
                }
                #pragma unroll
                for (int g = 0; g < 4; ++g) {
                    u16x8 v;
                    #pragma unroll
                    for (int j = 0; j < 8; ++j) {
                        int ch = g * 8 + j;
                        float acc = b1[ch];
                        #pragma unroll
                        for (int k = 0; k < 9; ++k) acc = fmaf(x[k], w1[ch * 9 + k], acc);
                        v[j] = f2h(fmaxf(acc, 0.f));
                    }
                    int slot = (pp * 4 + g) ^ (rr & 7);
                    *(u16x8*)(sm + rr * 64 + slot * 8) = v;
                }
            }
        }
    }
    __syncthreads();

    // ---- Phase B: conv2 in 2 chunks of 256 y2 rows, in-place write-back
    for (int cc = 0; cc < 2; ++cc) {
        int nl = cc * 256 + 32 * wv + ln;   // this lane's y2 row (B column)
        f32x16 acc2[2];
        #pragma unroll
        for (int mi = 0; mi < 2; ++mi)
            #pragma unroll
            for (int q = 0; q < 16; ++q) acc2[mi][q] = 0.f;
        f16x8 bfB[2];
        #pragma unroll 3
        for (int kk = 0; kk < 9; ++kk) {
            {
                int rr = nl + (kk >> 1);
                int pp = kk & 1;
                #pragma unroll
                for (int step = 0; step < 2; ++step) {
                    int slot = (pp * 4 + 2 * step + ls) ^ (rr & 7);
                    bfB[step] = *(const f16x8*)(sm + rr * 64 + slot * 8);
                }
            }
            const u16* ap = a2t + kk * 2048;
            #pragma unroll
            for (int step = 0; step < 2; ++step) {
                f16x8 af0 = *(const f16x8*)(ap + (2 * step + ls) * 512 + ln * 8);
                f16x8 af1 = *(const f16x8*)(ap + (2 * step + ls) * 512 + (32 + ln) * 8);
                acc2[0] = __builtin_amdgcn_mfma_f32_32x32x16_f16(af0, bfB[step], acc2[0], 0, 0, 0);
                acc2[1] = __builtin_amdgcn_mfma_f32_32x32x16_f16(af1, bfB[step], acc2[1], 0, 0, 0);
            }
        }
        __syncthreads();                    // all chunk reads done before overwrite
        int l2 = nl;
        int t2 = 2 * r0 - 4 + l2;
        bool valid = (t2 >= 0) && (t2 < T2);
        #pragma unroll
        for (int mi = 0; mi < 2; ++mi)
            #pragma unroll
            for (int q = 0; q < 4; ++q) {
                u16x4 v;
                #pragma unroll
                for (int d = 0; d < 4; ++d) {
                    int o = 32 * mi + 8 * q + 4 * ls + d;
                    float xv = valid ? fmaxf(acc2[mi][4 * q + d] + b2[o], 0.f) : 0.f;
                    v[d] = f2h(xv);
                }
                int gy = 4 * mi + q;
                int sy = gy ^ ((l2 >> 1) & 7);
                *(u16x4*)(sm + l2 * 64 + sy * 8 + ls * 4) = v;
            }
        __syncthreads();
    }

    // ---- Phase C: conv3 MFMA + mean-pool (M=128 x N=256; 2x4 waves of 64x64)
    const int mh = wv & 1, nh = wv >> 1;               // mh 0..1, nh 0..3
    f32x16 acc3[2][2];
    #pragma unroll
    for (int mi = 0; mi < 2; ++mi)
        #pragma unroll
        for (int ni = 0; ni < 2; ++ni)
            #pragma unroll
            for (int q = 0; q < 16; ++q) acc3[mi][ni][q] = 0.f;

    f16x8 bf[2][4];
    #pragma unroll 3
    for (int kk = 0; kk < 9; ++kk) {
        const u16* ap = a3t + kk * 8192;
        {
            #pragma unroll
            for (int ni = 0; ni < 2; ++ni) {
                int nl = 64 * nh + 32 * ni + ln;
                int l2 = 2 * nl + kk;                  // <= 518 < 520
                int rrC = nl + (kk >> 1);
                #pragma unroll
                for (int step = 0; step < 4; ++step) {
                    int sy = (2 * step + ls) ^ (rrC & 7);
                    bf[ni][step] = *(const f16x8*)(sm + l2 * 64 + sy * 8);
                }
            }
        }
        #pragma unroll
        for (int step = 0; step < 4; ++step) {
            f16x8 af0 = *(const f16x8*)(ap + (2 * step + ls) * 1024 + (64 * mh + ln) * 8);
            f16x8 af1 = *(const f16x8*)(ap + (2 * step + ls) * 1024 + (64 * mh + 32 + ln) * 8);
            #pragma unroll
            for (int ni = 0; ni < 2; ++ni) {
                acc3[0][ni] = __builtin_amdgcn_mfma_f32_32x32x16_f16(af0, bf[ni][step], acc3[0][ni], 0, 0, 0);
                acc3[1][ni] = __builtin_amdgcn_mfma_f32_32x32x16_f16(af1, bf[ni][step], acc3[1][ni], 0, 0, 0);
            }
        }
    }

    // epilogue: bias+relu, mask nl>=250, per-wave partials -> LDS reduce -> atomics
    float loc[32];
    #pragma unroll
    for (int mi = 0; mi < 2; ++mi)
        #pragma unroll
        for (int r = 0; r < 16; ++r) {
            int o = 64 * mh + 32 * mi + (r & 3) + 8 * (r >> 2) + 4 * ls;
            float bias = b3[o];
            float s = 0.f;
            #pragma unroll
            for (int ni = 0; ni < 2; ++ni) {
                int nl = 64 * nh + 32 * ni + ln;
                float v = fmaxf(acc3[mi][ni][r] + bias, 0.f);
                s += (nl < NT3) ? v : 0.f;
            }
            loc[mi * 16 + r] = s;
        }
    __syncthreads();
    float* smf = (float*)sm;               // [4 nh][128 o][32 ln] = 64 KB <= 66,560 B
    #pragma unroll
    for (int mi = 0; mi < 2; ++mi)
        #pragma unroll
        for (int r = 0; r < 16; ++r) {
            int o = 64 * mh + 32 * mi + (r & 3) + 8 * (r >> 2) + 4 * ls;
            smf[nh * 4096 + o * 32 + ln] = loc[mi * 16 + r];
        }
    __syncthreads();
    if (tid < 128) {
        int o = tid;
        float s = 0.f;
        #pragma unroll
        for (int j = 0; j < 32; ++j) {
            int col = (j + o) & 31;
            s += smf[o * 32 + col] + smf[4096 + o * 32 + col]
               + smf[8192 + o * 32 + col] + smf[12288 + o * 32 + col];
        }
        atomicAdd(&pooled[b * 128 + o], s);
    }

    // ---- tail: last block of this batch computes feats (was feats_k)
    // NOTE: no __threadfence() here (see kernel header comment). __syncthreads()
    // drains vmcnt(0), so all this block's device-scope pooled atomics have
    // completed at the coherent point before tid 0 increments cnt[b].
    __syncthreads();
    int* smi = (int*)sm;
    if (tid == 0) {
        int done = atomicAdd(&cnt[b], 1);
        smi[0] = (done == NBLKX - 1) ? 1 : 0;
    }
    __syncthreads();
    if (smi[0]) {
        float* pl = (float*)sm + 64;        // past the flag word
        if (tid < 128)
            pl[tid] = atomicAdd(&pooled[b * 128 + tid], 0.f) * (1.0f / 8000.0f);
        __syncthreads();
        if (tid < 128) {
            float feat = bl[tid];
            #pragma unroll 8
            for (int i = 0; i < 128; ++i) feat = fmaf(pl[i], wl[tid * 128 + i], feat);
            if (tid < 64) {                 // wave 0: amps + normalize
                float r = fmaxf(feat, 0.f);
                float s = r;
                #pragma unroll
                for (int off = 32; off > 0; off >>= 1) s += __shfl_xor(s, off);
                featbuf[b * 128 + tid] = r / (s + 1e-6f);
            } else {                        // noise_mag raw
                featbuf[b * 128 + tid] = feat;
            }
        }
    }
}

// ---------------- synthesis: Chebyshev sin-recurrence, 4 samples/thread, float4 I/O
// sin(2*pi*(h+1)*u) = 2*cos(2*pi*u)*sin(2*pi*h*u) - sin(2*pi*(h-1)*u)
__global__ __launch_bounds__(256) void synth_k(const float* __restrict__ f0,
                                               const float* __restrict__ wn,
                                               const float* __restrict__ featbuf,
                                               float* __restrict__ out) {
    const int tid = threadIdx.x;
    const int b = blockIdx.y;
    __shared__ float sa[64];
    __shared__ float nm[64];
    if (tid < 64) sa[tid] = featbuf[b * 128 + tid];
    else if (tid < 128) nm[tid - 64] = featbuf[b * 128 + tid];
    __syncthreads();

    const int t0v = blockIdx.x * 1024 + tid * 4;
    if (t0v >= T0) return;                  // last block tail (after the barrier)

    const float4 fv = *(const float4*)(f0 + (size_t)b * T0 + t0v);
    const float4 wv = *(const float4*)(wn + (size_t)b * T0 + t0v);

    float sc[4], sp[4], tc[4], ac[4];
    #pragma unroll
    for (int s = 0; s < 4; ++s) {
        // u = f0 * t * 4/63999 (linspace incl endpoint); frac in double (phase can
        // reach ~1e5 revolutions), then recurrence runs entirely in fp32.
        double u = (double)((&fv.x)[s]) * ((double)(t0v + s) * (4.0 / 63999.0));
        float uf = (float)(u - floor(u));
        sc[s] = __builtin_amdgcn_sinf(uf);           // sin(2*pi*u)
        tc[s] = 2.0f * __builtin_amdgcn_cosf(uf);    // 2*cos(2*pi*u)
        sp[s] = 0.f;
        ac[s] = 0.f;
    }
    #pragma unroll
    for (int h = 0; h < 64; ++h) {
        float a = sa[h];
        #pragma unroll
        for (int s = 0; s < 4; ++s) {
            ac[s] = fmaf(a, sc[s], ac[s]);
            float sn = fmaf(tc[s], sc[s], -sp[s]);   // sin(2*pi*(h+2)*u)
            sp[s] = sc[s];
            sc[s] = sn;
        }
    }
    float4 o;
    #pragma unroll
    for (int s = 0; s < 4; ++s)
        (&o.x)[s] = ac[s] + (&wv.x)[s] * nm[(t0v + s) / 1000];
    *(float4*)(out + (size_t)b * T0 + t0v) = o;
}

extern "C" void kernel_launch(void* const* d_in, const int* in_sizes, int n_in,
                              void* d_out, int out_size, void* d_ws, size_t ws_size,
                              hipStream_t stream) {
    const float* audio = (const float*)d_in[0];
    const float* f0    = (const float*)d_in[1];
    const float* wn    = (const float*)d_in[2];
    const float* w1    = (const float*)d_in[3];
    const float* b1    = (const float*)d_in[4];
    const float* w2    = (const float*)d_in[5];
    const float* b2    = (const float*)d_in[6];
    const float* w3    = (const float*)d_in[7];
    const float* b3    = (const float*)d_in[8];
    const float* wl    = (const float*)d_in[9];
    const float* bl    = (const float*)d_in[10];
    float* out = (float*)d_out;

    char* ws = (char*)d_ws;
    float* pooled  = (float*)(ws);                 // 2048 f32 (zeroed by prep_w_k)
    int*   cnt     = (int*)(ws + 8192);            // 16 int (zeroed by prep_w_k)
    float* featbuf = (float*)(ws + 8448);          // 2048 f32 (written by mega tail)
    u16*   a2t     = (u16*)(ws + 16640);           // 18432 u16
    u16*   a3t     = (u16*)(ws + 16640 + 36864);   // 73728 u16
    u16*   a1t     = (u16*)(ws + 16640 + 36864 + 147456);  // 512 u16

    prep_w_k<<<371, 256, 0, stream>>>(w1, b1, w2, w3, a1t, a2t, a3t, pooled, cnt);
    mega_k<<<dim3(NBLKX, BATCH), 512, 0, stream>>>(audio, w1, b1, a1t, a2t, b2, a3t, b3,
                                                   pooled, cnt, wl, bl, featbuf);
    synth_k<<<dim3((T0 + 1023) / 1024, BATCH), 256, 0, stream>>>(f0, wn, featbuf, out);
}